// Round 8
// baseline (960.744 us; speedup 1.0000x reference)
//
#include <hip/hip_runtime.h>
#include <math.h>

// MS-SSIM loss, 5 levels, 11x11 separable Gaussian, zero padding.
// R8: R5's h-first structure, with column handling hoisted out of the row
// loop: per-lane row-invariant clamped byte offsets + zero-masked per-lane
// h-weights (OOB column => weight 0 => exact zero-padding). One unified code
// path (no MASKED template), SADDR-form loads (uniform row base + voffset),
// and each row issues its 22 loads before the independent 40-FMA v-conv so
// the v-conv covers L1 latency. Loop body stays 11 rows (~15KB, I-cache fits).

#define NIMG 48            // 16 * 3
#define CH 32              // chunk height; divides 512,256,128,64,32
#define TWO_C1 2.0e-4f     // 2 * (0.01*1.0)^2
#define TWO_C2 1.8e-3f     // 2 * (0.03*1.0)^2

struct CInfo { int base[5]; int cnt[5]; };

#define FOR11(X) X(0) X(1) X(2) X(3) X(4) X(5) X(6) X(7) X(8) X(9) X(10)

#define DECLR(K) float rA##K = 0.f, rB##K = 0.f, rP##K = 0.f, rQ##K = 0.f;

// Per-lane strip invariants: clamped byte offset (load safety) and
// zero-masked horizontal weight (zero-padding semantics).
#define DECLOFF(K) \
  const int xo##K = gx + (K) - 5; \
  const unsigned off##K = (unsigned)(min(max(xo##K, 0), W - 1)) * 4u; \
  const float gv##K = ((unsigned)xo##K < (unsigned)W) ? G##K : 0.f;

#define TAPLOAD(K) \
  const float p##K = *(const float*)(rp_ + off##K); \
  const float t##K = *(const float*)(rt_ + off##K);

#define HACC(K) { \
    const float a_ = p##K + t##K, b_ = p##K - t##K; \
    hA_ = __builtin_fmaf(gv##K, a_, hA_); \
    hB_ = __builtin_fmaf(gv##K, b_, hB_); \
    hP_ = __builtin_fmaf(gv##K * a_, a_, hP_); \
    hQ_ = __builtin_fmaf(gv##K * b_, b_, hQ_); }

#define VSTEP(GK, S) \
    vA_ = __builtin_fmaf(GK, rA##S, vA_); vB_ = __builtin_fmaf(GK, rB##S, vB_); \
    vP_ = __builtin_fmaf(GK, rP##S, vP_); vQ_ = __builtin_fmaf(GK, rQ##S, vQ_);

// Load row r_, h-conv, write ring slot SW, fused 2x2 avg-pool (guarded).
#define HSTEP_BODY(SW) \
      const char* rp_ = (const char*)Pi + (size_t)r_ * W * 4; \
      const char* rt_ = (const char*)Ti + (size_t)r_ * W * 4; \
      FOR11(TAPLOAD) \
      float hA_ = 0.f, hB_ = 0.f, hP_ = 0.f, hQ_ = 0.f; \
      FOR11(HACC) \
      rA##SW = hA_; rB##SW = hB_; rP##SW = hP_; rQ##SW = hQ_; \
      if (DS) { \
        if (r_ >= y0 && r_ < y0 + CH) { \
          if ((r_ & 1) == 0) { pr = p5; tr = t5; } \
          else { \
            float sp_ = pr + p5, st_ = tr + t5; \
            sp_ += __shfl_xor(sp_, 1, 64); \
            st_ += __shfl_xor(st_, 1, 64); \
            if (((lane & 1) == 0) && (gx < W)) { \
              const size_t o_ = obase + (size_t)(r_ >> 1) * (size_t)(W >> 1) + \
                                (size_t)(gx >> 1); \
              dsP[o_] = sp_ * 0.25f; \
              dsT[o_] = st_ * 0.25f; \
            } } } }

// Prologue step: fill ring slot SW from input row R (no v-conv).
#define PSTEP(R, SW) do { \
    const int r_ = (R); \
    if ((unsigned)r_ < (unsigned)H) { \
      HSTEP_BODY(SW) \
    } else { rA##SW = 0.f; rB##SW = 0.f; rP##SW = 0.f; rQ##SW = 0.f; } \
  } while (0)

// Output row IROW: new input row -> slot SW; v-conv taps G0..G9 from slots
// S0..S9 (rows IROW-5..IROW+4), tap G10 from the just-written SW.
#define ROW_N(IROW, SW, S0,S1,S2,S3,S4,S5,S6,S7,S8,S9) do { \
    const int i_ = (IROW); \
    const int r_ = y0 + 5 + i_; \
    if ((unsigned)r_ < (unsigned)H) { \
      HSTEP_BODY(SW) \
    } else { rA##SW = 0.f; rB##SW = 0.f; rP##SW = 0.f; rQ##SW = 0.f; } \
    float vA_ = G0 * rA##S0, vB_ = G0 * rB##S0; \
    float vP_ = G0 * rP##S0, vQ_ = G0 * rQ##S0; \
    VSTEP(G1, S1) VSTEP(G2, S2) VSTEP(G3, S3) VSTEP(G4, S4) VSTEP(G5, S5) \
    VSTEP(G6, S6) VSTEP(G7, S7) VSTEP(G8, S8) VSTEP(G9, S9) \
    VSTEP(G10, SW) \
    const float A2_ = vA_ * vA_, B2_ = vB_ * vB_; \
    const float dAB_ = A2_ - B2_, sAB_ = A2_ + B2_; \
    const float cn_ = (vP_ - vQ_) - dAB_ + TWO_C2; \
    const float cd_ = (vP_ + vQ_) - sAB_ + TWO_C2; \
    float val_; \
    if (LAST) val_ = ((dAB_ + TWO_C1) * cn_) / ((sAB_ + TWO_C1) * cd_); \
    else      val_ = cn_ / cd_; \
    if ((i_ < CH) && (gx < W)) sum += val_; \
  } while (0)

template <int DS, int LAST>
__global__ __launch_bounds__(256, 3)
void msssim_level_k(const float* __restrict__ P, const float* __restrict__ T,
                    const int H, const int W, const int strips,
                    const int chunks, const int tasks,
                    float* __restrict__ dsP, float* __restrict__ dsT,
                    double* __restrict__ partial,
                    const float G0, const float G1, const float G2,
                    const float G3, const float G4, const float G5,
                    const float G6, const float G7, const float G8,
                    const float G9, const float G10) {
  __shared__ float sRed[4];
  const int tid = threadIdx.x;
  const int lane = tid & 63;
  const int wid = tid >> 6;
  float sum = 0.f;
  const int task = blockIdx.x * 4 + wid;
  if (task < tasks) {
    const int strip = task % strips;
    const int rem = task / strips;
    const int chunk = rem % chunks;
    const int img = rem / chunks;
    const int y0 = chunk * CH;
    const int gx = strip * 64 + lane;   // even strip offset -> ds lane parity
    const float* Pi = P + (size_t)img * H * W;
    const float* Ti = T + (size_t)img * H * W;
    const size_t obase = DS ? (size_t)img * (size_t)(H >> 1) * (W >> 1) : 0;

    FOR11(DECLOFF)        // off0..off10, gv0..gv10 (row-invariant)
    FOR11(DECLR)          // ring rA0..rQ10, named scalars
    float pr = 0.f, tr = 0.f;

    // Prologue: slots 0..9 <- rows y0-5 .. y0+4.
    PSTEP(y0 - 5, 0); PSTEP(y0 - 4, 1); PSTEP(y0 - 3, 2); PSTEP(y0 - 2, 3);
    PSTEP(y0 - 1, 4); PSTEP(y0 + 0, 5); PSTEP(y0 + 1, 6); PSTEP(y0 + 2, 7);
    PSTEP(y0 + 3, 8); PSTEP(y0 + 4, 9);

    // Main: 3 iterations x 11 rows (rows 0..32; row 32 excluded from sum).
    for (int base = 0; base < CH; base += 11) {
      ROW_N(base + 0, 10, 0,1,2,3,4,5,6,7,8,9);
      ROW_N(base + 1, 0,  1,2,3,4,5,6,7,8,9,10);
      ROW_N(base + 2, 1,  2,3,4,5,6,7,8,9,10,0);
      ROW_N(base + 3, 2,  3,4,5,6,7,8,9,10,0,1);
      ROW_N(base + 4, 3,  4,5,6,7,8,9,10,0,1,2);
      ROW_N(base + 5, 4,  5,6,7,8,9,10,0,1,2,3);
      ROW_N(base + 6, 5,  6,7,8,9,10,0,1,2,3,4);
      ROW_N(base + 7, 6,  7,8,9,10,0,1,2,3,4,5);
      ROW_N(base + 8, 7,  8,9,10,0,1,2,3,4,5,6);
      ROW_N(base + 9, 8,  9,10,0,1,2,3,4,5,6,7);
      ROW_N(base + 10, 9, 10,0,1,2,3,4,5,6,7,8);
    }
  }

#pragma unroll
  for (int off = 32; off; off >>= 1) sum += __shfl_down(sum, off, 64);
  if (lane == 0) sRed[wid] = sum;
  __syncthreads();
  if (tid == 0)
    partial[blockIdx.x] = (double)(sRed[0] + sRed[1] + sRed[2] + sRed[3]);
}

__global__ void msssim_combine_k(const double* __restrict__ partial,
                                 float* __restrict__ out, const CInfo ci) {
  const int lane = threadIdx.x & 63;
  double lv[5];
#pragma unroll
  for (int L = 0; L < 5; ++L) {
    double s = 0.0;
    for (int i = lane; i < ci.cnt[L]; i += 64) s += partial[ci.base[L] + i];
#pragma unroll
    for (int off = 32; off; off >>= 1) s += __shfl_down(s, off, 64);
    lv[L] = s;
  }
  if (lane == 0) {
    double ms = lv[4] / (48.0 * 32.0 * 32.0);
    ms *= pow(lv[0] / (48.0 * 512.0 * 512.0), (double)0.0448f);
    ms *= pow(lv[1] / (48.0 * 256.0 * 256.0), (double)0.2856f);
    ms *= pow(lv[2] / (48.0 * 128.0 * 128.0), (double)0.3001f);
    ms *= pow(lv[3] / (48.0 * 64.0 * 64.0),  (double)0.2363f);
    out[0] = (float)(1.0 - ms);
  }
}

extern "C" void kernel_launch(void* const* d_in, const int* in_sizes, int n_in,
                              void* d_out, int out_size, void* d_ws, size_t ws_size,
                              hipStream_t stream) {
  const float* pred = (const float*)d_in[0];
  const float* targ = (const float*)d_in[1];
  float* out = (float*)d_out;

  char* ws = (char*)d_ws;
  double* partial = (double*)ws;  // per-block partial sums, 32KB region
  size_t off = 32768;
  auto alloc = [&](size_t elems) {
    float* p = (float*)(ws + off);
    off += elems * sizeof(float);
    return p;
  };
  float* L1p = alloc((size_t)NIMG * 256 * 256);
  float* L1t = alloc((size_t)NIMG * 256 * 256);
  float* L2p = alloc((size_t)NIMG * 128 * 128);
  float* L2t = alloc((size_t)NIMG * 128 * 128);
  float* L3p = alloc((size_t)NIMG * 64 * 64);
  float* L3t = alloc((size_t)NIMG * 64 * 64);
  float* L4p = alloc((size_t)NIMG * 32 * 32);
  float* L4t = alloc((size_t)NIMG * 32 * 32);

  float g[11];
  {
    double gd[11], s = 0.0;
    for (int k = 0; k < 11; ++k) {
      const double c = (double)(k - 5);
      gd[k] = exp(-(c * c) / 4.5);  // 2*sigma^2 = 4.5
      s += gd[k];
    }
    for (int k = 0; k < 11; ++k) g[k] = (float)(gd[k] / s);
  }

  CInfo ci;
  int slotOff = 0;

  auto launchLevel = [&](const float* P, const float* T, int H, int W,
                         float* dP, float* dT, int L, bool last) {
    const int strips = (W + 63) / 64;
    const int chunks = H / CH;
    const int tasks = strips * chunks * NIMG;
    const int blocks = (tasks + 3) / 4;
    ci.base[L] = slotOff;
    ci.cnt[L] = blocks;
    if (last) {
      msssim_level_k<0, 1><<<blocks, 256, 0, stream>>>(
          P, T, H, W, strips, chunks, tasks, nullptr, nullptr,
          partial + slotOff, g[0], g[1], g[2], g[3], g[4], g[5], g[6], g[7],
          g[8], g[9], g[10]);
    } else {
      msssim_level_k<1, 0><<<blocks, 256, 0, stream>>>(
          P, T, H, W, strips, chunks, tasks, dP, dT,
          partial + slotOff, g[0], g[1], g[2], g[3], g[4], g[5], g[6], g[7],
          g[8], g[9], g[10]);
    }
    slotOff += blocks;
  };

  launchLevel(pred, targ, 512, 512, L1p, L1t, 0, false);
  launchLevel(L1p, L1t, 256, 256, L2p, L2t, 1, false);
  launchLevel(L2p, L2t, 128, 128, L3p, L3t, 2, false);
  launchLevel(L3p, L3t, 64, 64, L4p, L4t, 3, false);
  launchLevel(L4p, L4t, 32, 32, nullptr, nullptr, 4, true);

  msssim_combine_k<<<1, 64, 0, stream>>>(partial, out, ci);
}